// Round 1
// baseline (3759.047 us; speedup 1.0000x reference)
//
#include <hip/hip_runtime.h>

#define N_NODES 100000
#define N_EDGES 2000000
#define DIM 64

// ---------------------------------------------------------------------------
// deg[dst[e]] += 1
__global__ __launch_bounds__(256) void deg_kernel(const int* __restrict__ dst,
                                                  float* __restrict__ deg, int E) {
    int e = blockIdx.x * blockDim.x + threadIdx.x;
    if (e < E) unsafeAtomicAdd(&deg[dst[e]], 1.0f);
}

// ---------------------------------------------------------------------------
// agg[dst[e]] += h[src[e]]   (16 threads per edge, float4 per thread)
__global__ __launch_bounds__(256) void scatter_kernel(const int* __restrict__ src,
                                                      const int* __restrict__ dst,
                                                      const float* __restrict__ h,
                                                      float* __restrict__ agg, int E) {
    long long tid = (long long)blockIdx.x * blockDim.x + threadIdx.x;
    int e = (int)(tid >> 4);
    int c = (int)(tid & 15);
    if (e >= E) return;
    int s = src[e];
    int d = dst[e];
    const float4 v = *(const float4*)(h + (size_t)s * DIM + (size_t)c * 4);
    float* o = agg + (size_t)d * DIM + (size_t)c * 4;
    unsafeAtomicAdd(o + 0, v.x);
    unsafeAtomicAdd(o + 1, v.y);
    unsafeAtomicAdd(o + 2, v.z);
    unsafeAtomicAdd(o + 3, v.w);
}

// ---------------------------------------------------------------------------
// out[i] = maybe_relu( concat(h[i], agg[i]*inv_deg[i]) @ W + b )
// One wave (64 lanes) per node; 4 nodes per 256-thread block.
// W (128x64 = 32KB) staged in LDS; concat vector staged in LDS per wave.
// In-place safe when h == out (each wave reads only its own row before writing).
template <bool RELU>
__global__ __launch_bounds__(256) void linear_kernel(const float* __restrict__ h,
                                                     const float* __restrict__ agg,
                                                     const float* __restrict__ deg,
                                                     const float* __restrict__ W,
                                                     const float* __restrict__ b,
                                                     float* __restrict__ out) {
    __shared__ float WL[2 * DIM * DIM];     // 32 KB
    __shared__ float hcat[4][2 * DIM];      // 2 KB

    const int wave = threadIdx.x >> 6;
    const int lane = threadIdx.x & 63;
    const int node = blockIdx.x * 4 + wave;   // grid = N_NODES/4 exactly (100000 % 4 == 0)

    // cooperative W load (float4-vectorized): 8192 floats / 256 threads
    {
        const float4* Wv = (const float4*)W;
        float4* WLv = (float4*)WL;
        #pragma unroll
        for (int i = 0; i < (2 * DIM * DIM / 4) / 256; ++i)
            WLv[threadIdx.x + i * 256] = Wv[threadIdx.x + i * 256];
    }

    const float dg = deg[node];
    const float inv = 1.0f / fmaxf(dg, 1.0f);
    hcat[wave][lane]        = h[(size_t)node * DIM + lane];
    hcat[wave][DIM + lane]  = agg[(size_t)node * DIM + lane] * inv;
    __syncthreads();

    float acc = b[lane];
    #pragma unroll
    for (int k = 0; k < 2 * DIM; ++k) {
        acc = fmaf(hcat[wave][k], WL[k * DIM + lane], acc);
    }
    if (RELU) acc = fmaxf(acc, 0.0f);
    out[(size_t)node * DIM + lane] = acc;
}

// ---------------------------------------------------------------------------
extern "C" void kernel_launch(void* const* d_in, const int* in_sizes, int n_in,
                              void* d_out, int out_size, void* d_ws, size_t ws_size,
                              hipStream_t stream) {
    const float* x  = (const float*)d_in[0];
    const int*   ei = (const int*)d_in[1];
    const float* W0 = (const float*)d_in[2];
    const float* b0 = (const float*)d_in[3];
    const float* W1 = (const float*)d_in[4];
    const float* b1 = (const float*)d_in[5];
    float* out = (float*)d_out;

    const int* src = ei;            // edge_index[0]
    const int* dst = ei + N_EDGES;  // edge_index[1]

    char* ws = (char*)d_ws;
    const size_t deg_bytes = ((size_t)N_NODES * sizeof(float) + 255) & ~(size_t)255;
    float* deg = (float*)ws;
    float* agg = (float*)(ws + deg_bytes);
    const size_t agg_bytes = (size_t)N_NODES * DIM * sizeof(float);

    // zero deg + agg (workspace is re-poisoned to 0xAA before every launch)
    hipMemsetAsync(d_ws, 0, deg_bytes + agg_bytes, stream);

    // degrees
    deg_kernel<<<(N_EDGES + 255) / 256, 256, 0, stream>>>(dst, deg, N_EDGES);

    // ---- layer 0 ----
    {
        long long threads = (long long)N_EDGES * 16;
        scatter_kernel<<<(int)((threads + 255) / 256), 256, 0, stream>>>(src, dst, x, agg, N_EDGES);
    }
    linear_kernel<true><<<N_NODES / 4, 256, 0, stream>>>(x, agg, deg, W0, b0, out);

    // ---- layer 1 ----
    hipMemsetAsync(agg, 0, agg_bytes, stream);
    {
        long long threads = (long long)N_EDGES * 16;
        scatter_kernel<<<(int)((threads + 255) / 256), 256, 0, stream>>>(src, dst, out, agg, N_EDGES);
    }
    linear_kernel<false><<<N_NODES / 4, 256, 0, stream>>>(out, agg, deg, W1, b1, out);
}

// Round 2
// 716.239 us; speedup vs baseline: 5.2483x; 5.2483x over previous
//
#include <hip/hip_runtime.h>

#define N_NODES 100000
#define N_EDGES 2000000
#define DIM 64
#define SCAN_BLOCKS ((N_NODES + 255) / 256)   // 391

// ---------------------------------------------------------------------------
// deg[dst[e]] += 1  (int atomics)
__global__ __launch_bounds__(256) void deg_count(const int* __restrict__ dst,
                                                 int* __restrict__ deg) {
    int e = blockIdx.x * blockDim.x + threadIdx.x;
    if (e < N_EDGES) atomicAdd(&deg[dst[e]], 1);
}

// ---------------------------------------------------------------------------
// scan pass 1: per-block exclusive scan of deg -> row_ptr (local), block totals
__global__ __launch_bounds__(256) void scan1(const int* __restrict__ deg,
                                             int* __restrict__ row_ptr,
                                             int* __restrict__ blksum) {
    __shared__ int a[256];
    const int t = threadIdx.x;
    const int i = blockIdx.x * 256 + t;
    const int v = (i < N_NODES) ? deg[i] : 0;
    a[t] = v;
    __syncthreads();
    #pragma unroll
    for (int off = 1; off < 256; off <<= 1) {
        int u = (t >= off) ? a[t - off] : 0;
        __syncthreads();
        a[t] += u;
        __syncthreads();
    }
    if (i < N_NODES) row_ptr[i] = a[t] - v;   // local exclusive
    if (t == 255) blksum[blockIdx.x] = a[255];
}

// scan pass 2: single block exclusive scan of the 391 block sums
__global__ __launch_bounds__(512) void scan2(const int* __restrict__ blksum,
                                             int* __restrict__ blkoff) {
    __shared__ int a[512];
    const int t = threadIdx.x;
    const int v = (t < SCAN_BLOCKS) ? blksum[t] : 0;
    a[t] = v;
    __syncthreads();
    #pragma unroll
    for (int off = 1; off < 512; off <<= 1) {
        int u = (t >= off) ? a[t - off] : 0;
        __syncthreads();
        a[t] += u;
        __syncthreads();
    }
    if (t < SCAN_BLOCKS) blkoff[t] = a[t] - v;  // exclusive
}

// scan pass 3: add block offsets; also produce cursor copy and row_ptr[N]
__global__ __launch_bounds__(256) void scan3(int* __restrict__ row_ptr,
                                             const int* __restrict__ blkoff,
                                             int* __restrict__ cursor) {
    const int i = blockIdx.x * 256 + threadIdx.x;
    if (i < N_NODES) {
        int r = row_ptr[i] + blkoff[i >> 8];
        row_ptr[i] = r;
        cursor[i] = r;
    }
    if (i == 0) row_ptr[N_NODES] = N_EDGES;
}

// ---------------------------------------------------------------------------
// csr_src[cursor[dst[e]]++] = src[e]
__global__ __launch_bounds__(256) void fill_csr(const int* __restrict__ src,
                                                const int* __restrict__ dst,
                                                int* __restrict__ cursor,
                                                int* __restrict__ csr_src) {
    int e = blockIdx.x * blockDim.x + threadIdx.x;
    if (e < N_EDGES) {
        int p = atomicAdd(&cursor[dst[e]], 1);
        csr_src[p] = src[e];
    }
}

// ---------------------------------------------------------------------------
// Fused: agg = mean_{s in N(n)} h[s];  out[n] = maybe_relu([h[n]|agg] @ W + b)
// One wave per node, 4 nodes / 256-thread block. W (32 KB) staged in LDS.
template <bool RELU>
__global__ __launch_bounds__(256) void sage_layer(const float* __restrict__ h,
                                                  const int* __restrict__ row_ptr,
                                                  const int* __restrict__ csr_src,
                                                  const float* __restrict__ W,
                                                  const float* __restrict__ b,
                                                  float* __restrict__ out) {
    __shared__ float WL[2 * DIM * DIM];   // 32 KB
    __shared__ float hcat[4][2 * DIM];    // 2 KB

    const int wave = threadIdx.x >> 6;
    const int lane = threadIdx.x & 63;
    const int node = blockIdx.x * 4 + wave;   // 100000 % 4 == 0

    // cooperative W load (float4): 8192 floats / 256 threads = 8 iters
    {
        const float4* Wv = (const float4*)W;
        float4* WLv = (float4*)WL;
        #pragma unroll
        for (int i = 0; i < 8; ++i)
            WLv[threadIdx.x + i * 256] = Wv[threadIdx.x + i * 256];
    }

    const int rp0 = row_ptr[node];
    const int rp1 = row_ptr[node + 1];

    // gather-sum neighbor rows; neighbor indices loaded coalesced, shfl-broadcast
    float acc0 = 0.f, acc1 = 0.f;
    for (int base = rp0; base < rp1; base += 64) {
        const int cnt = min(rp1 - base, 64);
        const int idx = (lane < cnt) ? csr_src[base + lane] : 0;
        int j = 0;
        for (; j + 1 < cnt; j += 2) {
            const int s0 = __shfl(idx, j);
            const int s1 = __shfl(idx, j + 1);
            acc0 += h[(size_t)s0 * DIM + lane];
            acc1 += h[(size_t)s1 * DIM + lane];
        }
        if (j < cnt) acc0 += h[(size_t)__shfl(idx, j) * DIM + lane];
    }
    const float degf = (float)(rp1 - rp0);
    const float inv = 1.0f / fmaxf(degf, 1.0f);

    hcat[wave][lane]       = h[(size_t)node * DIM + lane];
    hcat[wave][DIM + lane] = (acc0 + acc1) * inv;
    __syncthreads();   // WL visibility (hcat is same-wave)

    float o = b[lane];
    #pragma unroll 16
    for (int k = 0; k < 2 * DIM; ++k)
        o = fmaf(hcat[wave][k], WL[k * DIM + lane], o);
    if (RELU) o = fmaxf(o, 0.f);
    out[(size_t)node * DIM + lane] = o;
}

// ---------------------------------------------------------------------------
extern "C" void kernel_launch(void* const* d_in, const int* in_sizes, int n_in,
                              void* d_out, int out_size, void* d_ws, size_t ws_size,
                              hipStream_t stream) {
    const float* x  = (const float*)d_in[0];
    const int*   ei = (const int*)d_in[1];
    const float* W0 = (const float*)d_in[2];
    const float* b0 = (const float*)d_in[3];
    const float* W1 = (const float*)d_in[4];
    const float* b1 = (const float*)d_in[5];
    float* out = (float*)d_out;

    const int* src = ei;            // edge_index[0]
    const int* dst = ei + N_EDGES;  // edge_index[1]

    // workspace layout (all 256B-aligned)
    char* ws = (char*)d_ws;
    auto alloc = [&](size_t bytes) {
        char* p = ws;
        ws += (bytes + 255) & ~(size_t)255;
        return p;
    };
    int*   deg     = (int*)alloc((size_t)N_NODES * 4);
    int*   row_ptr = (int*)alloc((size_t)(N_NODES + 1) * 4);
    int*   cursor  = (int*)alloc((size_t)N_NODES * 4);
    int*   blksum  = (int*)alloc((size_t)SCAN_BLOCKS * 4);
    int*   blkoff  = (int*)alloc((size_t)SCAN_BLOCKS * 4);
    int*   csr     = (int*)alloc((size_t)N_EDGES * 4);
    float* h1      = (float*)alloc((size_t)N_NODES * DIM * 4);

    // only deg needs zeroing
    hipMemsetAsync(deg, 0, (size_t)N_NODES * 4, stream);

    // ---- CSR build (shared by both layers) ----
    deg_count<<<(N_EDGES + 255) / 256, 256, 0, stream>>>(dst, deg);
    scan1<<<SCAN_BLOCKS, 256, 0, stream>>>(deg, row_ptr, blksum);
    scan2<<<1, 512, 0, stream>>>(blksum, blkoff);
    scan3<<<SCAN_BLOCKS, 256, 0, stream>>>(row_ptr, blkoff, cursor);
    fill_csr<<<(N_EDGES + 255) / 256, 256, 0, stream>>>(src, dst, cursor, csr);

    // ---- layer 0: x -> h1 (relu) ----
    sage_layer<true><<<N_NODES / 4, 256, 0, stream>>>(x, row_ptr, csr, W0, b0, h1);
    // ---- layer 1: h1 -> out ----
    sage_layer<false><<<N_NODES / 4, 256, 0, stream>>>(h1, row_ptr, csr, W1, b1, out);
}

// Round 3
// 583.134 us; speedup vs baseline: 6.4463x; 1.2283x over previous
//
#include <hip/hip_runtime.h>
#include <hip/hip_bf16.h>

#define N_NODES 100000
#define N_EDGES 2000000
#define DIM 64
#define SCAN_BLOCKS ((N_NODES + 255) / 256)   // 391

// ---------------------------------------------------------------------------
__global__ __launch_bounds__(256) void deg_count(const int* __restrict__ dst,
                                                 int* __restrict__ deg) {
    int e = blockIdx.x * blockDim.x + threadIdx.x;
    if (e < N_EDGES) atomicAdd(&deg[dst[e]], 1);
}

// scan pass 1: per-block exclusive scan of deg -> row_ptr (local), block totals
__global__ __launch_bounds__(256) void scan1(const int* __restrict__ deg,
                                             int* __restrict__ row_ptr,
                                             int* __restrict__ blksum) {
    __shared__ int a[256];
    const int t = threadIdx.x;
    const int i = blockIdx.x * 256 + t;
    const int v = (i < N_NODES) ? deg[i] : 0;
    a[t] = v;
    __syncthreads();
    #pragma unroll
    for (int off = 1; off < 256; off <<= 1) {
        int u = (t >= off) ? a[t - off] : 0;
        __syncthreads();
        a[t] += u;
        __syncthreads();
    }
    if (i < N_NODES) row_ptr[i] = a[t] - v;
    if (t == 255) blksum[blockIdx.x] = a[255];
}

__global__ __launch_bounds__(512) void scan2(const int* __restrict__ blksum,
                                             int* __restrict__ blkoff) {
    __shared__ int a[512];
    const int t = threadIdx.x;
    const int v = (t < SCAN_BLOCKS) ? blksum[t] : 0;
    a[t] = v;
    __syncthreads();
    #pragma unroll
    for (int off = 1; off < 512; off <<= 1) {
        int u = (t >= off) ? a[t - off] : 0;
        __syncthreads();
        a[t] += u;
        __syncthreads();
    }
    if (t < SCAN_BLOCKS) blkoff[t] = a[t] - v;
}

__global__ __launch_bounds__(256) void scan3(int* __restrict__ row_ptr,
                                             const int* __restrict__ blkoff,
                                             int* __restrict__ cursor) {
    const int i = blockIdx.x * 256 + threadIdx.x;
    if (i < N_NODES) {
        int r = row_ptr[i] + blkoff[i >> 8];
        row_ptr[i] = r;
        cursor[i] = r;
    }
    if (i == 0) row_ptr[N_NODES] = N_EDGES;
}

__global__ __launch_bounds__(256) void fill_csr(const int* __restrict__ src,
                                                const int* __restrict__ dst,
                                                int* __restrict__ cursor,
                                                int* __restrict__ csr_src) {
    int e = blockIdx.x * blockDim.x + threadIdx.x;
    if (e < N_EDGES) {
        int p = atomicAdd(&cursor[dst[e]], 1);
        csr_src[p] = src[e];
    }
}

// ---------------------------------------------------------------------------
// f32 -> bf16 copy (paired)
__global__ __launch_bounds__(256) void to_bf16(const float* __restrict__ in,
                                               __hip_bfloat162* __restrict__ out,
                                               int n2) {
    int i = blockIdx.x * blockDim.x + threadIdx.x;
    if (i < n2) {
        float2 v = ((const float2*)in)[i];
        out[i] = __float22bfloat162_rn(v);
    }
}

// ---------------------------------------------------------------------------
// Fused: agg = mean_{s in N(n)} hb[s] (bf16 gather, f32 accum);
//        out[n] = maybe_relu([h[n] | agg] @ W + b)   (f32)
// One wave per node, 8 nodes / 512-thread block (8 waves share the LDS W).
template <bool RELU, bool WB16>
__global__ __launch_bounds__(512) void sage_layer(const float* __restrict__ h,
                                                  const __hip_bfloat16* __restrict__ hb,
                                                  const int* __restrict__ row_ptr,
                                                  const int* __restrict__ csr_src,
                                                  const float* __restrict__ W,
                                                  const float* __restrict__ b,
                                                  float* __restrict__ out,
                                                  __hip_bfloat16* __restrict__ outb) {
    __shared__ float WL[2 * DIM * DIM];   // 32 KB
    __shared__ float hcat[8][2 * DIM];    // 4 KB

    const int wave = threadIdx.x >> 6;
    const int lane = threadIdx.x & 63;
    const int node = blockIdx.x * 8 + wave;   // 100000 % 8 == 0

    // cooperative W load: 2048 float4 / 512 threads = 4 iters
    {
        const float4* Wv = (const float4*)W;
        float4* WLv = (float4*)WL;
        #pragma unroll
        for (int i = 0; i < 4; ++i)
            WLv[threadIdx.x + i * 512] = Wv[threadIdx.x + i * 512];
    }
    __syncthreads();   // only barrier: W visibility; gathers proceed per-wave after

    const int rp0 = row_ptr[node];
    const int rp1 = row_ptr[node + 1];

    float a0 = 0.f, a1 = 0.f, a2 = 0.f, a3 = 0.f;
    for (int base = rp0; base < rp1; base += 64) {
        const int cnt = min(rp1 - base, 64);
        const int idx = (lane < cnt) ? csr_src[base + lane] : 0;
        int j = 0;
        for (; j + 3 < cnt; j += 4) {
            const int s0 = __shfl(idx, j);
            const int s1 = __shfl(idx, j + 1);
            const int s2 = __shfl(idx, j + 2);
            const int s3 = __shfl(idx, j + 3);
            a0 += __bfloat162float(hb[(size_t)s0 * DIM + lane]);
            a1 += __bfloat162float(hb[(size_t)s1 * DIM + lane]);
            a2 += __bfloat162float(hb[(size_t)s2 * DIM + lane]);
            a3 += __bfloat162float(hb[(size_t)s3 * DIM + lane]);
        }
        for (; j < cnt; ++j)
            a0 += __bfloat162float(hb[(size_t)__shfl(idx, j) * DIM + lane]);
    }
    const float inv = 1.0f / fmaxf((float)(rp1 - rp0), 1.0f);

    hcat[wave][lane]       = h[(size_t)node * DIM + lane];
    hcat[wave][DIM + lane] = ((a0 + a1) + (a2 + a3)) * inv;
    // hcat is same-wave read-after-write: no barrier needed (LDS ops in order)

    float o = b[lane];
    #pragma unroll
    for (int k = 0; k < 2 * DIM; ++k)
        o = fmaf(hcat[wave][k], WL[k * DIM + lane], o);
    if (RELU) o = fmaxf(o, 0.f);
    out[(size_t)node * DIM + lane] = o;
    if (WB16) outb[(size_t)node * DIM + lane] = __float2bfloat16(o);
}

// ---------------------------------------------------------------------------
extern "C" void kernel_launch(void* const* d_in, const int* in_sizes, int n_in,
                              void* d_out, int out_size, void* d_ws, size_t ws_size,
                              hipStream_t stream) {
    const float* x  = (const float*)d_in[0];
    const int*   ei = (const int*)d_in[1];
    const float* W0 = (const float*)d_in[2];
    const float* b0 = (const float*)d_in[3];
    const float* W1 = (const float*)d_in[4];
    const float* b1 = (const float*)d_in[5];
    float* out = (float*)d_out;

    const int* src = ei;            // edge_index[0]
    const int* dst = ei + N_EDGES;  // edge_index[1]

    char* ws = (char*)d_ws;
    auto alloc = [&](size_t bytes) {
        char* p = ws;
        ws += (bytes + 255) & ~(size_t)255;
        return p;
    };
    int*   deg     = (int*)alloc((size_t)N_NODES * 4);
    int*   row_ptr = (int*)alloc((size_t)(N_NODES + 1) * 4);
    int*   cursor  = (int*)alloc((size_t)N_NODES * 4);
    int*   blksum  = (int*)alloc((size_t)SCAN_BLOCKS * 4);
    int*   blkoff  = (int*)alloc((size_t)SCAN_BLOCKS * 4);
    int*   csr     = (int*)alloc((size_t)N_EDGES * 4);
    float* h1      = (float*)alloc((size_t)N_NODES * DIM * 4);
    __hip_bfloat16* xb  = (__hip_bfloat16*)alloc((size_t)N_NODES * DIM * 2);
    __hip_bfloat16* h1b = (__hip_bfloat16*)alloc((size_t)N_NODES * DIM * 2);

    hipMemsetAsync(deg, 0, (size_t)N_NODES * 4, stream);

    // ---- CSR build (shared by both layers) ----
    deg_count<<<(N_EDGES + 255) / 256, 256, 0, stream>>>(dst, deg);
    scan1<<<SCAN_BLOCKS, 256, 0, stream>>>(deg, row_ptr, blksum);
    scan2<<<1, 512, 0, stream>>>(blksum, blkoff);
    scan3<<<SCAN_BLOCKS, 256, 0, stream>>>(row_ptr, blkoff, cursor);
    fill_csr<<<(N_EDGES + 255) / 256, 256, 0, stream>>>(src, dst, cursor, csr);

    // bf16 copy of x for the gather path
    const int n2 = N_NODES * DIM / 2;
    to_bf16<<<(n2 + 255) / 256, 256, 0, stream>>>(x, (__hip_bfloat162*)xb, n2);

    // ---- layer 0: x -> h1 (relu), also emit bf16 copy for layer-1 gather ----
    sage_layer<true, true><<<N_NODES / 8, 512, 0, stream>>>(x, xb, row_ptr, csr,
                                                            W0, b0, h1, h1b);
    // ---- layer 1: h1 -> out ----
    sage_layer<false, false><<<N_NODES / 8, 512, 0, stream>>>(h1, h1b, row_ptr, csr,
                                                              W1, b1, out, nullptr);
}

// Round 4
// 327.414 us; speedup vs baseline: 11.4810x; 1.7810x over previous
//
#include <hip/hip_runtime.h>
#include <hip/hip_bf16.h>

#define N_NODES 100000
#define N_EDGES 2000000
#define DIM 64
#define NB 391                 // dst-buckets of 256 nodes = ceil(N_NODES/256)
#define SCAN_BLOCKS 391        // ceil(N_NODES/256) for the degree scan
#define EPB 4096               // edges per binning block
#define EPT 16                 // EPB / 256
#define BIN_BLOCKS ((N_EDGES + EPB - 1) / EPB)   // 489

typedef __attribute__((ext_vector_type(8))) short short8;
typedef __attribute__((ext_vector_type(4))) float f32x4;

// ---------------------------------------------------------------------------
// Bucket histogram (LDS-aggregated): ghist[dst>>8] counts
__global__ __launch_bounds__(256) void hist_kernel(const int* __restrict__ dst,
                                                   int* __restrict__ ghist) {
    __shared__ int lh[NB];
    const int t = threadIdx.x;
    for (int i = t; i < NB; i += 256) lh[i] = 0;
    __syncthreads();
    for (int e = blockIdx.x * 256 + t; e < N_EDGES; e += gridDim.x * 256)
        atomicAdd(&lh[dst[e] >> 8], 1);
    __syncthreads();
    for (int i = t; i < NB; i += 256)
        if (lh[i]) atomicAdd(&ghist[i], lh[i]);
}

// Exclusive scan of the 391 bucket counts -> boff (+ sentinel) and gbcur copy
__global__ __launch_bounds__(512) void scanH_kernel(const int* __restrict__ ghist,
                                                    int* __restrict__ boff,
                                                    int* __restrict__ gbcur) {
    __shared__ int a[512];
    const int t = threadIdx.x;
    const int v = (t < NB) ? ghist[t] : 0;
    a[t] = v;
    __syncthreads();
    #pragma unroll
    for (int off = 1; off < 512; off <<= 1) {
        int u = (t >= off) ? a[t - off] : 0;
        __syncthreads();
        a[t] += u;
        __syncthreads();
    }
    if (t < NB) {
        const int ex = a[t] - v;
        boff[t] = ex;
        gbcur[t] = ex;
    }
    if (t == 0) boff[NB] = N_EDGES;
}

// ---------------------------------------------------------------------------
// Binning pass: reorder 4096-edge chunks by bucket in LDS, write out
// bucket-contiguously (coalesced runs); fuses the degree count.
// Edge packed as (src<<8)|(dst&255) — bucket recovers the dst high bits.
__global__ __launch_bounds__(256) void binpass_kernel(const int* __restrict__ src,
                                                      const int* __restrict__ dst,
                                                      int* __restrict__ gbcur,
                                                      int* __restrict__ deg,
                                                      int* __restrict__ ebuf) {
    __shared__ int buf[EPB];        // 16 KB
    __shared__ short bufb[EPB];     // 8 KB (bucket of each reordered edge)
    __shared__ int lhist[NB], lscan[NB], lcur[NB], gbase[NB];  // ~6.3 KB
    const int t = threadIdx.x;
    const int e0 = blockIdx.x * EPB;
    const int cnt = min(EPB, N_EDGES - e0);

    for (int i = t; i < NB; i += 256) lhist[i] = 0;
    __syncthreads();

    int ls[EPT], ld[EPT];
    #pragma unroll
    for (int k = 0; k < EPT; ++k) {
        const int o = t + k * 256;
        if (o < cnt) {
            ls[k] = src[e0 + o];
            ld[k] = dst[e0 + o];
            atomicAdd(&lhist[ld[k] >> 8], 1);
        } else ld[k] = -1;
    }
    __syncthreads();
    if (t == 0) {                     // serial exclusive scan of 391 counts
        int run = 0;
        for (int i = 0; i < NB; ++i) { lscan[i] = run; run += lhist[i]; }
    }
    __syncthreads();
    for (int i = t; i < NB; i += 256) {
        const int c = lhist[i];
        gbase[i] = c ? atomicAdd(&gbcur[i], c) : 0;
        lcur[i] = lscan[i];
    }
    __syncthreads();
    #pragma unroll
    for (int k = 0; k < EPT; ++k) {
        if (ld[k] >= 0) {
            const int b = ld[k] >> 8;
            const int p = atomicAdd(&lcur[b], 1);
            buf[p]  = (ls[k] << 8) | (ld[k] & 255);
            bufb[p] = (short)b;
        }
    }
    __syncthreads();
    for (int i = t; i < cnt; i += 256) {
        const int pk = buf[i];
        const int b  = bufb[i];
        ebuf[gbase[b] + (i - lscan[b])] = pk;
        atomicAdd(&deg[(b << 8) | (pk & 255)], 1);
    }
}

// ---------------------------------------------------------------------------
// Degree scan -> row_ptr (3 passes)
__global__ __launch_bounds__(256) void scan1(const int* __restrict__ deg,
                                             int* __restrict__ row_ptr,
                                             int* __restrict__ blksum) {
    __shared__ int a[256];
    const int t = threadIdx.x;
    const int i = blockIdx.x * 256 + t;
    const int v = (i < N_NODES) ? deg[i] : 0;
    a[t] = v;
    __syncthreads();
    #pragma unroll
    for (int off = 1; off < 256; off <<= 1) {
        int u = (t >= off) ? a[t - off] : 0;
        __syncthreads();
        a[t] += u;
        __syncthreads();
    }
    if (i < N_NODES) row_ptr[i] = a[t] - v;
    if (t == 255) blksum[blockIdx.x] = a[255];
}

__global__ __launch_bounds__(512) void scan2(const int* __restrict__ blksum,
                                             int* __restrict__ blkoff) {
    __shared__ int a[512];
    const int t = threadIdx.x;
    const int v = (t < SCAN_BLOCKS) ? blksum[t] : 0;
    a[t] = v;
    __syncthreads();
    #pragma unroll
    for (int off = 1; off < 512; off <<= 1) {
        int u = (t >= off) ? a[t - off] : 0;
        __syncthreads();
        a[t] += u;
        __syncthreads();
    }
    if (t < SCAN_BLOCKS) blkoff[t] = a[t] - v;
}

__global__ __launch_bounds__(256) void scan3(int* __restrict__ row_ptr,
                                             const int* __restrict__ blkoff) {
    const int i = blockIdx.x * 256 + threadIdx.x;
    if (i < N_NODES) row_ptr[i] += blkoff[i >> 8];
    if (i == 0) row_ptr[N_NODES] = N_EDGES;
}

// ---------------------------------------------------------------------------
// Final CSR fill: one block per bucket; cursors in LDS; csr writes land in a
// ~20 KB L2-resident window owned by this block.
__global__ __launch_bounds__(256) void fillpass_kernel(const int* __restrict__ ebuf,
                                                       const int* __restrict__ boff,
                                                       const int* __restrict__ row_ptr,
                                                       int* __restrict__ csr) {
    __shared__ int cur[256];
    const int b = blockIdx.x;
    const int t = threadIdx.x;
    const int nbase = b << 8;
    if (nbase + t < N_NODES) cur[t] = row_ptr[nbase + t];
    __syncthreads();
    const int end = boff[b + 1];
    for (int i = boff[b] + t; i < end; i += 256) {
        const int pk = ebuf[i];
        const int p = atomicAdd(&cur[pk & 255], 1);
        csr[p] = pk >> 8;
    }
}

// ---------------------------------------------------------------------------
// f32 -> bf16 (paired)
__global__ __launch_bounds__(256) void to_bf16(const float* __restrict__ in,
                                               __hip_bfloat162* __restrict__ out,
                                               int n2) {
    int i = blockIdx.x * blockDim.x + threadIdx.x;
    if (i < n2) {
        float2 v = ((const float2*)in)[i];
        out[i] = __float22bfloat162_rn(v);
    }
}

// ---------------------------------------------------------------------------
// Pre-pack W0,W1 into MFMA B-fragment layout (bf16):
// wfrag[layer][nt][kc][lane][j] = W[kc*32 + (lane>>4)*8 + j][nt*16 + (lane&15)]
__global__ __launch_bounds__(256) void wprep_kernel(const float* __restrict__ W0,
                                                    const float* __restrict__ W1,
                                                    __hip_bfloat16* __restrict__ wfrag) {
    const int tid = blockIdx.x * 256 + threadIdx.x;   // 16384 total
    const int j    = tid & 7;
    const int lane = (tid >> 3) & 63;
    const int kc   = (tid >> 9) & 3;
    const int nt   = (tid >> 11) & 3;
    const int l    = tid >> 13;
    const int k = kc * 32 + (lane >> 4) * 8 + j;
    const int n = nt * 16 + (lane & 15);
    const float* W = l ? W1 : W0;
    wfrag[tid] = __float2bfloat16(W[k * 64 + n]);
}

// ---------------------------------------------------------------------------
// Gather: agg[node] = mean of neighbor rows (bf16 table, f32 accum).
// One wave per node. Lanes 0-31 / 32-63 each service one neighbor of a pair
// via bf16x2 (4 B) loads -> one global_load covers 2 neighbor rows (256 B).
__global__ __launch_bounds__(256) void gather_kernel(const unsigned int* __restrict__ hb2,
                                                     const int* __restrict__ row_ptr,
                                                     const int* __restrict__ csr,
                                                     unsigned int* __restrict__ aggb2) {
    const int wave = threadIdx.x >> 6;
    const int lane = threadIdx.x & 63;
    const int node = blockIdx.x * 4 + wave;   // 100000 % 4 == 0
    const int rp0 = row_ptr[node];
    const int rp1 = row_ptr[node + 1];
    const int half = lane >> 5;
    const int d2 = lane & 31;

    float ax = 0.f, ay = 0.f;
    for (int base = rp0; base < rp1; base += 64) {
        const int cnt = min(rp1 - base, 64);
        const int idx = (lane < cnt) ? csr[base + lane] : 0;
        int j = 0;
        for (; j + 8 <= cnt; j += 8) {       // 8 neighbors in flight
            const int s0 = __shfl(idx, j + 0 + half);
            const int s1 = __shfl(idx, j + 2 + half);
            const int s2 = __shfl(idx, j + 4 + half);
            const int s3 = __shfl(idx, j + 6 + half);
            const unsigned int u0 = hb2[(size_t)s0 * 32 + d2];
            const unsigned int u1 = hb2[(size_t)s1 * 32 + d2];
            const unsigned int u2 = hb2[(size_t)s2 * 32 + d2];
            const unsigned int u3 = hb2[(size_t)s3 * 32 + d2];
            ax += __uint_as_float(u0 << 16); ay += __uint_as_float(u0 & 0xffff0000u);
            ax += __uint_as_float(u1 << 16); ay += __uint_as_float(u1 & 0xffff0000u);
            ax += __uint_as_float(u2 << 16); ay += __uint_as_float(u2 & 0xffff0000u);
            ax += __uint_as_float(u3 << 16); ay += __uint_as_float(u3 & 0xffff0000u);
        }
        for (; j + 2 <= cnt; j += 2) {
            const int s = __shfl(idx, j + half);
            const unsigned int u = hb2[(size_t)s * 32 + d2];
            ax += __uint_as_float(u << 16); ay += __uint_as_float(u & 0xffff0000u);
        }
        if (j < cnt) {                        // odd remainder: lower half only
            const int s = __shfl(idx, j);
            if (half == 0) {
                const unsigned int u = hb2[(size_t)s * 32 + d2];
                ax += __uint_as_float(u << 16); ay += __uint_as_float(u & 0xffff0000u);
            }
        }
    }
    // combine the two half-wave partial sums
    const float ox = ax + __shfl(ax, lane + 32);
    const float oy = ay + __shfl(ay, lane + 32);
    if (lane < 32) {
        const float inv = 1.0f / fmaxf((float)(rp1 - rp0), 1.0f);
        __hip_bfloat162 o = __float22bfloat162_rn(make_float2(ox * inv, oy * inv));
        aggb2[(size_t)node * 32 + d2] = *(unsigned int*)&o;
    }
}

// ---------------------------------------------------------------------------
// Linear layer as MFMA GEMM: [M=100k x K=128] @ [K=128 x N=64], A = [hb | aggb]
// (bf16), B pre-packed fragments, f32 accumulate, bias+relu fused.
// Block = 4 waves, each wave one 16-row M-tile, looping the four 16-col N-tiles.
template <bool RELU, bool OUTF32>
__global__ __launch_bounds__(256) void gemm_kernel(const unsigned short* __restrict__ hb,
                                                   const unsigned short* __restrict__ aggb,
                                                   const unsigned short* __restrict__ wfrag,
                                                   const float* __restrict__ bias,
                                                   float* __restrict__ outf,
                                                   unsigned short* __restrict__ outb) {
    const int wave = threadIdx.x >> 6;
    const int lane = threadIdx.x & 63;
    const int m0 = (blockIdx.x * 4 + wave) * 16;
    const int quad = lane >> 4;
    const int lrow = lane & 15;
    const int m = min(m0 + lrow, N_NODES - 1);   // clamped A-row (stores guarded)

    short8 bf[4][4];
    #pragma unroll
    for (int nt = 0; nt < 4; ++nt)
        #pragma unroll
        for (int kc = 0; kc < 4; ++kc)
            bf[nt][kc] = *(const short8*)(wfrag + (size_t)((nt * 4 + kc) * 64 + lane) * 8);

    f32x4 acc[4];
    #pragma unroll
    for (int nt = 0; nt < 4; ++nt) acc[nt] = f32x4{0.f, 0.f, 0.f, 0.f};

    #pragma unroll
    for (int kc = 0; kc < 4; ++kc) {
        const unsigned short* ap = (kc < 2)
            ? (hb   + (size_t)m * 64 + kc * 32 + quad * 8)
            : (aggb + (size_t)m * 64 + (kc - 2) * 32 + quad * 8);
        const short8 af = *(const short8*)ap;
        #pragma unroll
        for (int nt = 0; nt < 4; ++nt)
            acc[nt] = __builtin_amdgcn_mfma_f32_16x16x32_bf16(af, bf[nt][kc], acc[nt], 0, 0, 0);
    }

    #pragma unroll
    for (int nt = 0; nt < 4; ++nt) {
        const float bv = bias[nt * 16 + lrow];
        #pragma unroll
        for (int r = 0; r < 4; ++r) {
            const int mr = m0 + quad * 4 + r;
            if (mr < N_NODES) {
                float v = acc[nt][r] + bv;
                if (RELU) v = fmaxf(v, 0.f);
                const size_t off = (size_t)mr * 64 + nt * 16 + lrow;
                if (OUTF32) {
                    outf[off] = v;
                } else {
                    __hip_bfloat16 hv = __float2bfloat16(v);
                    outb[off] = *(unsigned short*)&hv;
                }
            }
        }
    }
}

// ---------------------------------------------------------------------------
extern "C" void kernel_launch(void* const* d_in, const int* in_sizes, int n_in,
                              void* d_out, int out_size, void* d_ws, size_t ws_size,
                              hipStream_t stream) {
    const float* x  = (const float*)d_in[0];
    const int*   ei = (const int*)d_in[1];
    const float* W0 = (const float*)d_in[2];
    const float* b0 = (const float*)d_in[3];
    const float* W1 = (const float*)d_in[4];
    const float* b1 = (const float*)d_in[5];
    float* out = (float*)d_out;

    const int* src = ei;            // edge_index[0]
    const int* dst = ei + N_EDGES;  // edge_index[1]

    char* ws = (char*)d_ws;
    auto alloc = [&](size_t bytes) {
        char* p = ws;
        ws += (bytes + 255) & ~(size_t)255;
        return p;
    };
    int* ghist   = (int*)alloc((size_t)NB * 4);
    int* boff    = (int*)alloc((size_t)(NB + 1) * 4);
    int* gbcur   = (int*)alloc((size_t)NB * 4);
    int* deg     = (int*)alloc((size_t)N_NODES * 4);
    int* row_ptr = (int*)alloc((size_t)(N_NODES + 1) * 4);
    int* blksum  = (int*)alloc((size_t)SCAN_BLOCKS * 4);
    int* blkoff  = (int*)alloc((size_t)SCAN_BLOCKS * 4);
    int* ebuf    = (int*)alloc((size_t)N_EDGES * 4);
    int* csr     = (int*)alloc((size_t)N_EDGES * 4);
    unsigned short* xb    = (unsigned short*)alloc((size_t)N_NODES * DIM * 2);
    unsigned short* aggb  = (unsigned short*)alloc((size_t)N_NODES * DIM * 2);
    unsigned short* h1b   = (unsigned short*)alloc((size_t)N_NODES * DIM * 2);
    __hip_bfloat16* wfrag = (__hip_bfloat16*)alloc((size_t)2 * 8192 * 2);

    hipMemsetAsync(ghist, 0, (size_t)NB * 4, stream);
    hipMemsetAsync(deg, 0, (size_t)N_NODES * 4, stream);

    // ---- CSR build (bucketed counting sort) ----
    hist_kernel<<<256, 256, 0, stream>>>(dst, ghist);
    scanH_kernel<<<1, 512, 0, stream>>>(ghist, boff, gbcur);
    binpass_kernel<<<BIN_BLOCKS, 256, 0, stream>>>(src, dst, gbcur, deg, ebuf);
    scan1<<<SCAN_BLOCKS, 256, 0, stream>>>(deg, row_ptr, blksum);
    scan2<<<1, 512, 0, stream>>>(blksum, blkoff);
    scan3<<<SCAN_BLOCKS, 256, 0, stream>>>(row_ptr, blkoff);
    fillpass_kernel<<<NB, 256, 0, stream>>>(ebuf, boff, row_ptr, csr);

    // ---- precompute bf16 x and W fragments ----
    const int n2 = N_NODES * DIM / 2;
    to_bf16<<<(n2 + 255) / 256, 256, 0, stream>>>(x, (__hip_bfloat162*)xb, n2);
    wprep_kernel<<<64, 256, 0, stream>>>(W0, W1, wfrag);

    const int gemm_blocks = (N_NODES + 63) / 64;   // 1563

    // ---- layer 0: gather(xb) -> aggb; GEMM -> h1b (relu, bf16) ----
    gather_kernel<<<N_NODES / 4, 256, 0, stream>>>((const unsigned int*)xb, row_ptr, csr,
                                                   (unsigned int*)aggb);
    gemm_kernel<true, false><<<gemm_blocks, 256, 0, stream>>>(
        xb, aggb, (const unsigned short*)wfrag, b0, nullptr, h1b);

    // ---- layer 1: gather(h1b) -> aggb; GEMM -> out (f32) ----
    gather_kernel<<<N_NODES / 4, 256, 0, stream>>>((const unsigned int*)h1b, row_ptr, csr,
                                                   (unsigned int*)aggb);
    gemm_kernel<false, true><<<gemm_blocks, 256, 0, stream>>>(
        h1b, aggb, (const unsigned short*)wfrag + 8192, b1, out, nullptr);
}

// Round 5
// 266.625 us; speedup vs baseline: 14.0986x; 1.2280x over previous
//
#include <hip/hip_runtime.h>
#include <hip/hip_bf16.h>

#define N_NODES 100000
#define N_EDGES 2000000
#define DIM 64
#define NB 391                 // dst-buckets of 256 nodes
#define EPB 4096               // edges per binning block
#define EPT 16                 // EPB / 256
#define BIN_BLOCKS ((N_EDGES + EPB - 1) / EPB)   // 489
#define XCONV_BLOCKS (N_NODES * DIM / 2 / 256)   // 12500

typedef __attribute__((ext_vector_type(8))) short short8;
typedef __attribute__((ext_vector_type(4))) float f32x4;

// ---------------------------------------------------------------------------
// Bucket histogram (LDS-aggregated): ghist[dst>>8] counts
__global__ __launch_bounds__(256) void hist_kernel(const int* __restrict__ dst,
                                                   int* __restrict__ ghist) {
    __shared__ int lh[NB];
    const int t = threadIdx.x;
    for (int i = t; i < NB; i += 256) lh[i] = 0;
    __syncthreads();
    for (int e = blockIdx.x * 256 + t; e < N_EDGES; e += gridDim.x * 256)
        atomicAdd(&lh[dst[e] >> 8], 1);
    __syncthreads();
    for (int i = t; i < NB; i += 256)
        if (lh[i]) atomicAdd(&ghist[i], lh[i]);
}

// Exclusive scan of 391 bucket counts -> boff (+ sentinel) and gbcur copy
__global__ __launch_bounds__(512) void scanH_kernel(const int* __restrict__ ghist,
                                                    int* __restrict__ boff,
                                                    int* __restrict__ gbcur) {
    __shared__ int a[512];
    const int t = threadIdx.x;
    const int v = (t < NB) ? ghist[t] : 0;
    a[t] = v;
    __syncthreads();
    #pragma unroll
    for (int off = 1; off < 512; off <<= 1) {
        int u = (t >= off) ? a[t - off] : 0;
        __syncthreads();
        a[t] += u;
        __syncthreads();
    }
    if (t < NB) {
        const int ex = a[t] - v;
        boff[t] = ex;
        gbcur[t] = ex;
    }
    if (t == 0) boff[NB] = N_EDGES;
}

// ---------------------------------------------------------------------------
// Binning pass: reorder 4096-edge chunks by bucket in LDS (parallel Blelloch
// scan over the 391 bucket counts), write bucket-contiguous runs to ebuf.
// Edge packed as (src<<8)|(dst&255).
__global__ __launch_bounds__(256) void binpass_kernel(const int* __restrict__ src,
                                                      const int* __restrict__ dst,
                                                      int* __restrict__ gbcur,
                                                      int* __restrict__ ebuf) {
    __shared__ int buf[EPB];        // 16 KB
    __shared__ short bufb[EPB];     // 8 KB
    __shared__ int a[512];          // hist -> exclusive scan (padded)
    __shared__ int lscan[NB], lcur[NB], gbase[NB];
    const int t = threadIdx.x;
    const int e0 = blockIdx.x * EPB;
    const int cnt = min(EPB, N_EDGES - e0);

    for (int i = t; i < 512; i += 256) a[i] = 0;
    __syncthreads();

    int ls[EPT], ld[EPT];
    #pragma unroll
    for (int k = 0; k < EPT; ++k) {
        const int o = t + k * 256;
        if (o < cnt) {
            ls[k] = src[e0 + o];
            ld[k] = dst[e0 + o];
            atomicAdd(&a[ld[k] >> 8], 1);
        } else ld[k] = -1;
    }
    __syncthreads();

    // Blelloch exclusive scan over a[0..511]
    #pragma unroll
    for (int d = 1; d < 512; d <<= 1) {
        const int idx = (t + 1) * 2 * d - 1;
        if (idx < 512) a[idx] += a[idx - d];
        __syncthreads();
    }
    if (t == 0) a[511] = 0;
    __syncthreads();
    #pragma unroll
    for (int d = 256; d >= 1; d >>= 1) {
        const int idx = (t + 1) * 2 * d - 1;
        if (idx < 512) {
            const int tmp = a[idx - d];
            a[idx - d] = a[idx];
            a[idx] += tmp;
        }
        __syncthreads();
    }
    // a[i] = exclusive scan; local count of bucket i = a[i+1]-a[i]
    for (int i = t; i < NB; i += 256) {
        const int c = a[i + 1] - a[i];
        lscan[i] = a[i];
        lcur[i]  = a[i];
        gbase[i] = c ? atomicAdd(&gbcur[i], c) : 0;
    }
    __syncthreads();

    #pragma unroll
    for (int k = 0; k < EPT; ++k) {
        if (ld[k] >= 0) {
            const int b = ld[k] >> 8;
            const int p = atomicAdd(&lcur[b], 1);
            buf[p]  = (ls[k] << 8) | (ld[k] & 255);
            bufb[p] = (short)b;
        }
    }
    __syncthreads();
    for (int i = t; i < cnt; i += 256) {
        const int pk = buf[i];
        const int b  = bufb[i];
        ebuf[gbase[b] + (i - lscan[b])] = pk;
    }
}

// ---------------------------------------------------------------------------
// Per-bucket pass: derive row_ptr from local degree scan (edges are
// bucket-sorted so node offsets = boff[b] + local exclusive scan), then fill
// csr with LDS cursors (writes land in a ~20 KB L2-resident window).
__global__ __launch_bounds__(256) void fillpass_kernel(const int* __restrict__ ebuf,
                                                       const int* __restrict__ boff,
                                                       int* __restrict__ row_ptr,
                                                       int* __restrict__ csr) {
    __shared__ int cnt[256];
    __shared__ int s[256];
    __shared__ int cur[256];
    const int b = blockIdx.x;
    const int t = threadIdx.x;
    const int nbase = b << 8;
    const int start = boff[b];
    const int end   = boff[b + 1];

    cnt[t] = 0;
    __syncthreads();
    for (int i = start + t; i < end; i += 256)
        atomicAdd(&cnt[ebuf[i] & 255], 1);
    __syncthreads();

    // inclusive Hillis-Steele scan of cnt -> s
    const int v = cnt[t];
    s[t] = v;
    __syncthreads();
    #pragma unroll
    for (int off = 1; off < 256; off <<= 1) {
        int u = (t >= off) ? s[t - off] : 0;
        __syncthreads();
        s[t] += u;
        __syncthreads();
    }
    const int rp = start + s[t] - v;   // global exclusive offset for node nbase+t
    if (nbase + t < N_NODES) row_ptr[nbase + t] = rp;
    if (b == NB - 1 && t == 0) row_ptr[N_NODES] = N_EDGES;
    cur[t] = rp;
    __syncthreads();

    for (int i = start + t; i < end; i += 256) {
        const int pk = ebuf[i];
        const int p = atomicAdd(&cur[pk & 255], 1);
        csr[p] = pk >> 8;
    }
}

// ---------------------------------------------------------------------------
// Fused prep: blocks [0, XCONV_BLOCKS) convert x -> bf16 pairs;
// the last 64 blocks pack W0,W1 into MFMA B-fragment layout:
// wfrag[layer][nt][kc][lane][j] = W[kc*32 + (lane>>4)*8 + j][nt*16 + (lane&15)]
__global__ __launch_bounds__(256) void prep_kernel(const float* __restrict__ x,
                                                   unsigned int* __restrict__ xb2,
                                                   const float* __restrict__ W0,
                                                   const float* __restrict__ W1,
                                                   __hip_bfloat16* __restrict__ wfrag) {
    const int bid = blockIdx.x;
    if (bid < XCONV_BLOCKS) {
        const int i = bid * 256 + threadIdx.x;
        float2 v = ((const float2*)x)[i];
        __hip_bfloat162 o = __float22bfloat162_rn(v);
        xb2[i] = *(unsigned int*)&o;
    } else {
        const int tid = (bid - XCONV_BLOCKS) * 256 + threadIdx.x;  // 16384 total
        const int j    = tid & 7;
        const int lane = (tid >> 3) & 63;
        const int kc   = (tid >> 9) & 3;
        const int nt   = (tid >> 11) & 3;
        const int l    = tid >> 13;
        const int k = kc * 32 + (lane >> 4) * 8 + j;
        const int n = nt * 16 + (lane & 15);
        const float* W = l ? W1 : W0;
        wfrag[tid] = __float2bfloat16(W[k * 64 + n]);
    }
}

// ---------------------------------------------------------------------------
// Gather: agg[node] = mean of neighbor rows (bf16 table, f32 accum).
// One wave per node; half-waves each service one neighbor of a pair via
// bf16x2 loads; up to 8 loads in flight per wave.
__global__ __launch_bounds__(256) void gather_kernel(const unsigned int* __restrict__ hb2,
                                                     const int* __restrict__ row_ptr,
                                                     const int* __restrict__ csr,
                                                     unsigned int* __restrict__ aggb2) {
    const int wave = threadIdx.x >> 6;
    const int lane = threadIdx.x & 63;
    const int node = blockIdx.x * 4 + wave;   // 100000 % 4 == 0
    const int rp0 = row_ptr[node];
    const int rp1 = row_ptr[node + 1];
    const int half = lane >> 5;
    const int d2 = lane & 31;

    float ax = 0.f, ay = 0.f;
    for (int base = rp0; base < rp1; base += 64) {
        const int cnt = min(rp1 - base, 64);
        const int idx = (lane < cnt) ? csr[base + lane] : 0;
        int j = 0;
        for (; j + 16 <= cnt; j += 16) {     // 8 loads in flight
            int sidx[8];
            unsigned int u[8];
            #pragma unroll
            for (int q = 0; q < 8; ++q) sidx[q] = __shfl(idx, j + 2 * q + half);
            #pragma unroll
            for (int q = 0; q < 8; ++q) u[q] = hb2[(size_t)sidx[q] * 32 + d2];
            #pragma unroll
            for (int q = 0; q < 8; ++q) {
                ax += __uint_as_float(u[q] << 16);
                ay += __uint_as_float(u[q] & 0xffff0000u);
            }
        }
        for (; j + 2 <= cnt; j += 2) {
            const int sidx = __shfl(idx, j + half);
            const unsigned int u = hb2[(size_t)sidx * 32 + d2];
            ax += __uint_as_float(u << 16);
            ay += __uint_as_float(u & 0xffff0000u);
        }
        if (j < cnt) {                        // odd remainder: lower half only
            const int sidx = __shfl(idx, j);
            if (half == 0) {
                const unsigned int u = hb2[(size_t)sidx * 32 + d2];
                ax += __uint_as_float(u << 16);
                ay += __uint_as_float(u & 0xffff0000u);
            }
        }
    }
    const float ox = ax + __shfl(ax, lane + 32);
    const float oy = ay + __shfl(ay, lane + 32);
    if (lane < 32) {
        const float inv = 1.0f / fmaxf((float)(rp1 - rp0), 1.0f);
        __hip_bfloat162 o = __float22bfloat162_rn(make_float2(ox * inv, oy * inv));
        aggb2[(size_t)node * 32 + d2] = *(unsigned int*)&o;
    }
}

// ---------------------------------------------------------------------------
// Linear layer as MFMA GEMM: [M=100k x K=128] @ [K=128 x N=64], A = [hb|aggb]
// bf16, B pre-packed fragments, f32 accumulate, bias+relu fused.
template <bool RELU, bool OUTF32>
__global__ __launch_bounds__(256) void gemm_kernel(const unsigned short* __restrict__ hb,
                                                   const unsigned short* __restrict__ aggb,
                                                   const unsigned short* __restrict__ wfrag,
                                                   const float* __restrict__ bias,
                                                   float* __restrict__ outf,
                                                   unsigned short* __restrict__ outb) {
    const int wave = threadIdx.x >> 6;
    const int lane = threadIdx.x & 63;
    const int m0 = (blockIdx.x * 4 + wave) * 16;
    const int quad = lane >> 4;
    const int lrow = lane & 15;
    const int m = min(m0 + lrow, N_NODES - 1);   // clamped A-row (stores guarded)

    short8 bf[4][4];
    #pragma unroll
    for (int nt = 0; nt < 4; ++nt)
        #pragma unroll
        for (int kc = 0; kc < 4; ++kc)
            bf[nt][kc] = *(const short8*)(wfrag + (size_t)((nt * 4 + kc) * 64 + lane) * 8);

    f32x4 acc[4];
    #pragma unroll
    for (int nt = 0; nt < 4; ++nt) acc[nt] = f32x4{0.f, 0.f, 0.f, 0.f};

    #pragma unroll
    for (int kc = 0; kc < 4; ++kc) {
        const unsigned short* ap = (kc < 2)
            ? (hb   + (size_t)m * 64 + kc * 32 + quad * 8)
            : (aggb + (size_t)m * 64 + (kc - 2) * 32 + quad * 8);
        const short8 af = *(const short8*)ap;
        #pragma unroll
        for (int nt = 0; nt < 4; ++nt)
            acc[nt] = __builtin_amdgcn_mfma_f32_16x16x32_bf16(af, bf[nt][kc], acc[nt], 0, 0, 0);
    }

    #pragma unroll
    for (int nt = 0; nt < 4; ++nt) {
        const float bv = bias[nt * 16 + lrow];
        #pragma unroll
        for (int r = 0; r < 4; ++r) {
            const int mr = m0 + quad * 4 + r;
            if (mr < N_NODES) {
                float v = acc[nt][r] + bv;
                if (RELU) v = fmaxf(v, 0.f);
                const size_t off = (size_t)mr * 64 + nt * 16 + lrow;
                if (OUTF32) {
                    outf[off] = v;
                } else {
                    __hip_bfloat16 hv = __float2bfloat16(v);
                    outb[off] = *(unsigned short*)&hv;
                }
            }
        }
    }
}

// ---------------------------------------------------------------------------
extern "C" void kernel_launch(void* const* d_in, const int* in_sizes, int n_in,
                              void* d_out, int out_size, void* d_ws, size_t ws_size,
                              hipStream_t stream) {
    const float* x  = (const float*)d_in[0];
    const int*   ei = (const int*)d_in[1];
    const float* W0 = (const float*)d_in[2];
    const float* b0 = (const float*)d_in[3];
    const float* W1 = (const float*)d_in[4];
    const float* b1 = (const float*)d_in[5];
    float* out = (float*)d_out;

    const int* src = ei;            // edge_index[0]
    const int* dst = ei + N_EDGES;  // edge_index[1]

    char* ws = (char*)d_ws;
    auto alloc = [&](size_t bytes) {
        char* p = ws;
        ws += (bytes + 255) & ~(size_t)255;
        return p;
    };
    int* ghist   = (int*)alloc((size_t)NB * 4);
    int* boff    = (int*)alloc((size_t)(NB + 1) * 4);
    int* gbcur   = (int*)alloc((size_t)NB * 4);
    int* row_ptr = (int*)alloc((size_t)(N_NODES + 1) * 4);
    int* ebuf    = (int*)alloc((size_t)N_EDGES * 4);
    int* csr     = (int*)alloc((size_t)N_EDGES * 4);
    unsigned short* xb    = (unsigned short*)alloc((size_t)N_NODES * DIM * 2);
    unsigned short* aggb  = (unsigned short*)alloc((size_t)N_NODES * DIM * 2);
    unsigned short* h1b   = (unsigned short*)alloc((size_t)N_NODES * DIM * 2);
    __hip_bfloat16* wfrag = (__hip_bfloat16*)alloc((size_t)2 * 8192 * 2);

    hipMemsetAsync(ghist, 0, (size_t)NB * 4, stream);

    // ---- CSR build (bucketed counting sort; row_ptr derived in fillpass) ----
    hist_kernel<<<256, 256, 0, stream>>>(dst, ghist);
    scanH_kernel<<<1, 512, 0, stream>>>(ghist, boff, gbcur);
    binpass_kernel<<<BIN_BLOCKS, 256, 0, stream>>>(src, dst, gbcur, ebuf);
    fillpass_kernel<<<NB, 256, 0, stream>>>(ebuf, boff, row_ptr, csr);

    // ---- bf16 x + W fragments ----
    prep_kernel<<<XCONV_BLOCKS + 64, 256, 0, stream>>>(x, (unsigned int*)xb,
                                                       W0, W1, wfrag);

    const int gemm_blocks = (N_NODES + 63) / 64;   // 1563

    // ---- layer 0 ----
    gather_kernel<<<N_NODES / 4, 256, 0, stream>>>((const unsigned int*)xb, row_ptr, csr,
                                                   (unsigned int*)aggb);
    gemm_kernel<true, false><<<gemm_blocks, 256, 0, stream>>>(
        xb, aggb, (const unsigned short*)wfrag, b0, nullptr, h1b);

    // ---- layer 1 ----
    gather_kernel<<<N_NODES / 4, 256, 0, stream>>>((const unsigned int*)h1b, row_ptr, csr,
                                                   (unsigned int*)aggb);
    gemm_kernel<false, true><<<gemm_blocks, 256, 0, stream>>>(
        h1b, aggb, (const unsigned short*)wfrag + 8192, b1, out, nullptr);
}

// Round 6
// 245.734 us; speedup vs baseline: 15.2972x; 1.0850x over previous
//
#include <hip/hip_runtime.h>
#include <hip/hip_bf16.h>

#define N_NODES 100000
#define N_EDGES 2000000
#define DIM 64
#define NB 391                 // dst-buckets of 256 nodes
#define CAP 8192               // padded per-bucket ebuf capacity (mean 5115, +42 sigma)
#define EPB 4096               // edges per binning block
#define EPT 16                 // EPB / 256
#define BIN_BLOCKS ((N_EDGES + EPB - 1) / EPB)   // 489
#define XCONV_BLOCKS (N_NODES * DIM / 2 / 256)   // 12500

typedef __attribute__((ext_vector_type(8))) short short8;
typedef __attribute__((ext_vector_type(4))) float f32x4;

// ---------------------------------------------------------------------------
// Combined: blocks [0,BIN_BLOCKS) bin edges into padded per-bucket runs of
// ebuf (zero-based cursor atomics -> no pre-histogram needed); next 12500
// blocks convert x -> bf16; last 64 blocks pack W0/W1 into MFMA B-fragments.
__global__ __launch_bounds__(256) void binprep_kernel(const int* __restrict__ src,
                                                      const int* __restrict__ dst,
                                                      int* __restrict__ gbcur,
                                                      int* __restrict__ ebuf,
                                                      const float* __restrict__ x,
                                                      unsigned int* __restrict__ xb2,
                                                      const float* __restrict__ W0,
                                                      const float* __restrict__ W1,
                                                      __hip_bfloat16* __restrict__ wfrag) {
    __shared__ int buf[EPB];        // 16 KB
    __shared__ short bufb[EPB];     // 8 KB
    __shared__ int a[512];
    __shared__ int lscan[NB], lcur[NB], gbase[NB];

    const int bid = blockIdx.x;
    if (bid >= BIN_BLOCKS) {
        const int pb = bid - BIN_BLOCKS;
        if (pb < XCONV_BLOCKS) {                 // x -> bf16 pairs
            const int i = pb * 256 + threadIdx.x;
            float2 v = ((const float2*)x)[i];
            __hip_bfloat162 o = __float22bfloat162_rn(v);
            xb2[i] = *(unsigned int*)&o;
        } else {                                  // W fragment pack
            const int tid = (pb - XCONV_BLOCKS) * 256 + threadIdx.x;  // 16384
            const int j    = tid & 7;
            const int lane = (tid >> 3) & 63;
            const int kc   = (tid >> 9) & 3;
            const int nt   = (tid >> 11) & 3;
            const int l    = tid >> 13;
            const int k = kc * 32 + (lane >> 4) * 8 + j;
            const int n = nt * 16 + (lane & 15);
            const float* W = l ? W1 : W0;
            wfrag[tid] = __float2bfloat16(W[k * 64 + n]);
        }
        return;
    }

    // ---- binning block ----
    const int t = threadIdx.x;
    const int e0 = bid * EPB;
    const int cnt = min(EPB, N_EDGES - e0);

    for (int i = t; i < 512; i += 256) a[i] = 0;
    __syncthreads();

    int ls[EPT], ld[EPT];
    #pragma unroll
    for (int k = 0; k < EPT; ++k) {
        const int o = t + k * 256;
        if (o < cnt) {
            ls[k] = src[e0 + o];
            ld[k] = dst[e0 + o];
            atomicAdd(&a[ld[k] >> 8], 1);
        } else ld[k] = -1;
    }
    __syncthreads();

    // Blelloch exclusive scan over a[0..511]
    #pragma unroll
    for (int d = 1; d < 512; d <<= 1) {
        const int idx = (t + 1) * 2 * d - 1;
        if (idx < 512) a[idx] += a[idx - d];
        __syncthreads();
    }
    if (t == 0) a[511] = 0;
    __syncthreads();
    #pragma unroll
    for (int d = 256; d >= 1; d >>= 1) {
        const int idx = (t + 1) * 2 * d - 1;
        if (idx < 512) {
            const int tmp = a[idx - d];
            a[idx - d] = a[idx];
            a[idx] += tmp;
        }
        __syncthreads();
    }
    for (int i = t; i < NB; i += 256) {
        const int c = a[i + 1] - a[i];
        lscan[i] = a[i];
        lcur[i]  = a[i];
        gbase[i] = c ? atomicAdd(&gbcur[i], c) : 0;   // zero-based run base
    }
    __syncthreads();

    #pragma unroll
    for (int k = 0; k < EPT; ++k) {
        if (ld[k] >= 0) {
            const int b = ld[k] >> 8;
            const int p = atomicAdd(&lcur[b], 1);
            buf[p]  = (ls[k] << 8) | (ld[k] & 255);
            bufb[p] = (short)b;
        }
    }
    __syncthreads();
    for (int i = t; i < cnt; i += 256) {
        const int pk = buf[i];
        const int b  = bufb[i];
        ebuf[b * CAP + gbase[b] + (i - lscan[b])] = pk;
    }
}

// ---------------------------------------------------------------------------
// Exclusive scan of the 391 final bucket counts -> dense CSR bucket offsets
__global__ __launch_bounds__(512) void scanC_kernel(const int* __restrict__ gbcur,
                                                    int* __restrict__ dboff) {
    __shared__ int a[512];
    const int t = threadIdx.x;
    const int v = (t < NB) ? gbcur[t] : 0;
    a[t] = v;
    __syncthreads();
    #pragma unroll
    for (int off = 1; off < 512; off <<= 1) {
        int u = (t >= off) ? a[t - off] : 0;
        __syncthreads();
        a[t] += u;
        __syncthreads();
    }
    if (t < NB) dboff[t] = a[t] - v;
    if (t == 0) dboff[NB] = N_EDGES;
}

// ---------------------------------------------------------------------------
// Per-bucket: derive row_ptr (local degree count + scan over 256 nodes) and
// fill csr densely with LDS cursors (writes land in an L2-resident window).
__global__ __launch_bounds__(256) void fillpass_kernel(const int* __restrict__ ebuf,
                                                       const int* __restrict__ gbcur,
                                                       const int* __restrict__ dboff,
                                                       int* __restrict__ row_ptr,
                                                       int* __restrict__ csr) {
    __shared__ int cnt[256];
    __shared__ int s[256];
    __shared__ int cur[256];
    const int b = blockIdx.x;
    const int t = threadIdx.x;
    const int nbase = b << 8;
    const int ecnt = gbcur[b];
    const int estart = b * CAP;
    const int dbase = dboff[b];

    cnt[t] = 0;
    __syncthreads();
    for (int i = t; i < ecnt; i += 256)
        atomicAdd(&cnt[ebuf[estart + i] & 255], 1);
    __syncthreads();

    const int v = cnt[t];
    s[t] = v;
    __syncthreads();
    #pragma unroll
    for (int off = 1; off < 256; off <<= 1) {
        int u = (t >= off) ? s[t - off] : 0;
        __syncthreads();
        s[t] += u;
        __syncthreads();
    }
    const int rp = dbase + s[t] - v;
    if (nbase + t < N_NODES) row_ptr[nbase + t] = rp;
    if (b == NB - 1 && t == 0) row_ptr[N_NODES] = N_EDGES;
    cur[t] = rp;
    __syncthreads();

    for (int i = t; i < ecnt; i += 256) {
        const int pk = ebuf[estart + i];
        const int p = atomicAdd(&cur[pk & 255], 1);
        csr[p] = pk >> 8;
    }
}

// ---------------------------------------------------------------------------
// Gather: agg[node] = mean of neighbor rows (bf16 table, f32 accum).
// One wave per node; quarter-waves (16 lanes x 8 B = 128 B row) each service
// one neighbor of a group of 4 -> one load instruction covers 4 rows.
__global__ __launch_bounds__(256) void gather_kernel(const uint2* __restrict__ hb8,
                                                     const int* __restrict__ row_ptr,
                                                     const int* __restrict__ csr,
                                                     uint2* __restrict__ agg8) {
    const int wave = threadIdx.x >> 6;
    const int lane = threadIdx.x & 63;
    const int node = blockIdx.x * 4 + wave;   // 100000 % 4 == 0
    const int rp0 = row_ptr[node];
    const int rp1 = row_ptr[node + 1];
    const int q = lane >> 4;                  // quarter
    const int r = lane & 15;                  // 8B-chunk within row

    float a0 = 0.f, a1 = 0.f, a2 = 0.f, a3 = 0.f;
    for (int base = rp0; base < rp1; base += 64) {
        const int cnt = min(rp1 - base, 64);
        const int idx = (lane < cnt) ? __builtin_nontemporal_load(csr + base + lane) : 0;
        int j = 0;
        for (; j + 16 <= cnt; j += 16) {      // 4 loads in flight, 16 neighbors
            const int s0 = __shfl(idx, j + q);
            const int s1 = __shfl(idx, j + 4 + q);
            const int s2 = __shfl(idx, j + 8 + q);
            const int s3 = __shfl(idx, j + 12 + q);
            const uint2 u0 = hb8[(size_t)s0 * 16 + r];
            const uint2 u1 = hb8[(size_t)s1 * 16 + r];
            const uint2 u2 = hb8[(size_t)s2 * 16 + r];
            const uint2 u3 = hb8[(size_t)s3 * 16 + r];
            a0 += __uint_as_float(u0.x << 16); a1 += __uint_as_float(u0.x & 0xffff0000u);
            a2 += __uint_as_float(u0.y << 16); a3 += __uint_as_float(u0.y & 0xffff0000u);
            a0 += __uint_as_float(u1.x << 16); a1 += __uint_as_float(u1.x & 0xffff0000u);
            a2 += __uint_as_float(u1.y << 16); a3 += __uint_as_float(u1.y & 0xffff0000u);
            a0 += __uint_as_float(u2.x << 16); a1 += __uint_as_float(u2.x & 0xffff0000u);
            a2 += __uint_as_float(u2.y << 16); a3 += __uint_as_float(u2.y & 0xffff0000u);
            a0 += __uint_as_float(u3.x << 16); a1 += __uint_as_float(u3.x & 0xffff0000u);
            a2 += __uint_as_float(u3.y << 16); a3 += __uint_as_float(u3.y & 0xffff0000u);
        }
        for (; j < cnt; j += 4) {             // tail, quarters masked
            const int jj = j + q;
            const int s = __shfl(idx, jj & 63);
            const uint2 u = hb8[(size_t)s * 16 + r];
            if (jj < cnt) {
                a0 += __uint_as_float(u.x << 16); a1 += __uint_as_float(u.x & 0xffff0000u);
                a2 += __uint_as_float(u.y << 16); a3 += __uint_as_float(u.y & 0xffff0000u);
            }
        }
    }
    // combine the 4 quarter-wave partials (lanes differing in bits 4,5)
    a0 += __shfl_xor(a0, 16); a0 += __shfl_xor(a0, 32);
    a1 += __shfl_xor(a1, 16); a1 += __shfl_xor(a1, 32);
    a2 += __shfl_xor(a2, 16); a2 += __shfl_xor(a2, 32);
    a3 += __shfl_xor(a3, 16); a3 += __shfl_xor(a3, 32);
    if (lane < 16) {
        const float inv = 1.0f / fmaxf((float)(rp1 - rp0), 1.0f);
        __hip_bfloat162 p0 = __float22bfloat162_rn(make_float2(a0 * inv, a1 * inv));
        __hip_bfloat162 p1 = __float22bfloat162_rn(make_float2(a2 * inv, a3 * inv));
        uint2 o;
        o.x = *(unsigned int*)&p0;
        o.y = *(unsigned int*)&p1;
        agg8[(size_t)node * 16 + r] = o;
    }
}

// ---------------------------------------------------------------------------
// Linear layer as MFMA GEMM: [M=100k x K=128] @ [K=128 x N=64], A = [hb|aggb]
// bf16, B pre-packed fragments, f32 accumulate, bias+relu fused.
template <bool RELU, bool OUTF32>
__global__ __launch_bounds__(256) void gemm_kernel(const unsigned short* __restrict__ hb,
                                                   const unsigned short* __restrict__ aggb,
                                                   const unsigned short* __restrict__ wfrag,
                                                   const float* __restrict__ bias,
                                                   float* __restrict__ outf,
                                                   unsigned short* __restrict__ outb) {
    const int wave = threadIdx.x >> 6;
    const int lane = threadIdx.x & 63;
    const int m0 = (blockIdx.x * 4 + wave) * 16;
    const int quad = lane >> 4;
    const int lrow = lane & 15;
    const int m = min(m0 + lrow, N_NODES - 1);   // clamped A-row (stores guarded)

    short8 bf[4][4];
    #pragma unroll
    for (int nt = 0; nt < 4; ++nt)
        #pragma unroll
        for (int kc = 0; kc < 4; ++kc)
            bf[nt][kc] = *(const short8*)(wfrag + (size_t)((nt * 4 + kc) * 64 + lane) * 8);

    f32x4 acc[4];
    #pragma unroll
    for (int nt = 0; nt < 4; ++nt) acc[nt] = f32x4{0.f, 0.f, 0.f, 0.f};

    #pragma unroll
    for (int kc = 0; kc < 4; ++kc) {
        const unsigned short* ap = (kc < 2)
            ? (hb   + (size_t)m * 64 + kc * 32 + quad * 8)
            : (aggb + (size_t)m * 64 + (kc - 2) * 32 + quad * 8);
        const short8 af = *(const short8*)ap;
        #pragma unroll
        for (int nt = 0; nt < 4; ++nt)
            acc[nt] = __builtin_amdgcn_mfma_f32_16x16x32_bf16(af, bf[nt][kc], acc[nt], 0, 0, 0);
    }

    #pragma unroll
    for (int nt = 0; nt < 4; ++nt) {
        const float bv = bias[nt * 16 + lrow];
        #pragma unroll
        for (int r = 0; r < 4; ++r) {
            const int mr = m0 + quad * 4 + r;
            if (mr < N_NODES) {
                float v = acc[nt][r] + bv;
                if (RELU) v = fmaxf(v, 0.f);
                const size_t off = (size_t)mr * 64 + nt * 16 + lrow;
                if (OUTF32) {
                    outf[off] = v;
                } else {
                    __hip_bfloat16 hv = __float2bfloat16(v);
                    outb[off] = *(unsigned short*)&hv;
                }
            }
        }
    }
}

// ---------------------------------------------------------------------------
extern "C" void kernel_launch(void* const* d_in, const int* in_sizes, int n_in,
                              void* d_out, int out_size, void* d_ws, size_t ws_size,
                              hipStream_t stream) {
    const float* x  = (const float*)d_in[0];
    const int*   ei = (const int*)d_in[1];
    const float* W0 = (const float*)d_in[2];
    const float* b0 = (const float*)d_in[3];
    const float* W1 = (const float*)d_in[4];
    const float* b1 = (const float*)d_in[5];
    float* out = (float*)d_out;

    const int* src = ei;            // edge_index[0]
    const int* dst = ei + N_EDGES;  // edge_index[1]

    char* ws = (char*)d_ws;
    auto alloc = [&](size_t bytes) {
        char* p = ws;
        ws += (bytes + 255) & ~(size_t)255;
        return p;
    };
    int* gbcur   = (int*)alloc((size_t)NB * 4);
    int* dboff   = (int*)alloc((size_t)(NB + 1) * 4);
    int* row_ptr = (int*)alloc((size_t)(N_NODES + 1) * 4);
    int* ebuf    = (int*)alloc((size_t)NB * CAP * 4);     // 12.8 MB padded
    int* csr     = (int*)alloc((size_t)N_EDGES * 4);
    unsigned short* xb    = (unsigned short*)alloc((size_t)N_NODES * DIM * 2);
    unsigned short* aggb  = (unsigned short*)alloc((size_t)N_NODES * DIM * 2);
    unsigned short* h1b   = (unsigned short*)alloc((size_t)N_NODES * DIM * 2);
    __hip_bfloat16* wfrag = (__hip_bfloat16*)alloc((size_t)2 * 8192 * 2);

    hipMemsetAsync(gbcur, 0, (size_t)NB * 4, stream);

    // ---- CSR build + prep (fused): bin -> scan counts -> fill ----
    binprep_kernel<<<BIN_BLOCKS + XCONV_BLOCKS + 64, 256, 0, stream>>>(
        src, dst, gbcur, ebuf, x, (unsigned int*)xb, W0, W1, wfrag);
    scanC_kernel<<<1, 512, 0, stream>>>(gbcur, dboff);
    fillpass_kernel<<<NB, 256, 0, stream>>>(ebuf, gbcur, dboff, row_ptr, csr);

    const int gemm_blocks = (N_NODES + 63) / 64;   // 1563

    // ---- layer 0 ----
    gather_kernel<<<N_NODES / 4, 256, 0, stream>>>((const uint2*)xb, row_ptr, csr,
                                                   (uint2*)aggb);
    gemm_kernel<true, false><<<gemm_blocks, 256, 0, stream>>>(
        xb, aggb, (const unsigned short*)wfrag, b0, nullptr, h1b);

    // ---- layer 1 ----
    gather_kernel<<<N_NODES / 4, 256, 0, stream>>>((const uint2*)h1b, row_ptr, csr,
                                                   (uint2*)aggb);
    gemm_kernel<false, true><<<gemm_blocks, 256, 0, stream>>>(
        h1b, aggb, (const unsigned short*)wfrag + 8192, b1, out, nullptr);
}